// Round 1
// baseline (2820.968 us; speedup 1.0000x reference)
//
#include <hip/hip_runtime.h>
#include <hip/hip_bf16.h>

// Problem constants
#define B_ 64
#define S_ 128
#define C_ 32
#define D_ 512
#define V_ 20000

typedef __bf16  bf16x8 __attribute__((ext_vector_type(8)));
typedef float   f32x4  __attribute__((ext_vector_type(4)));
typedef __fp16  v2h    __attribute__((ext_vector_type(2)));

// ---- workspace layout (bytes, all 16B aligned) ----
// x_bf16 [8192][512]          : 8,388,608
// U_bf16 [2048][512]          : 2,097,152
// Wg fp16 swizzled [4][64][512][8] : 2,097,152
// Wd fp16 swizzled [64][512][8]    : 524,288
// cb fp32 [2048]              : 8,192
// tf fp32 [8192][512]         : 16,777,216
// ux fp32 [8192][2048]        : 67,108,864   -> total ~97 MB
#define OFF_XBF 0ull
#define OFF_UBF 8388608ull
#define OFF_WG  10485760ull
#define OFF_WD  12582912ull
#define OFF_CB  13107200ull
#define OFF_TF  13115392ull
#define OFF_UX  29892608ull

// ---------------- prep kernels ----------------

// W_all [2048][512] fp32 -> fp16, layout [((g*64+k8)*512+d)*8+j] = W[(g*512+d)][k8*8+j]
__global__ void k_prep_wall(const float* __restrict__ W, _Float16* __restrict__ o)
{
    int i = blockIdx.x * 256 + threadIdx.x;      // 0 .. 1048575
    int j = i & 7;
    int rest = i >> 3;
    int d  = rest & 511; rest >>= 9;
    int k8 = rest & 63;
    int g  = rest >> 6;
    o[i] = (_Float16)W[(size_t)(g * 512 + d) * 512 + k8 * 8 + j];
}

// W_d [512][512] fp32 -> fp16, layout [((k8*512)+d)*8+j] = W_d[d][k8*8+j]
__global__ void k_prep_wd(const float* __restrict__ W, _Float16* __restrict__ o)
{
    int i = blockIdx.x * 256 + threadIdx.x;      // 0 .. 262143
    int j = i & 7;
    int rest = i >> 3;
    int d  = rest & 511;
    int k8 = rest >> 9;
    o[i] = (_Float16)W[(size_t)d * 512 + k8 * 8 + j];
}

// U_all [2048][512] fp32 -> bf16 (same layout)
__global__ void k_prep_u(const float* __restrict__ U, __hip_bfloat16* __restrict__ o)
{
    int i = blockIdx.x * 256 + threadIdx.x;      // 0 .. 1048575
    o[i] = __float2bfloat16(U[i]);
}

// combined gate bias = W_all_b + U_all_b
__global__ void k_prep_cb(const float* __restrict__ a, const float* __restrict__ b,
                          float* __restrict__ o)
{
    int i = blockIdx.x * 256 + threadIdx.x;      // 0 .. 2047
    o[i] = a[i] + b[i];
}

// ---------------- embedding gather-sum -> x bf16 ----------------
__global__ void k_embed(const float* __restrict__ emb, const int* __restrict__ seqs,
                        __hip_bfloat16* __restrict__ xbf)
{
    int bs = blockIdx.x;           // b*S + s
    int t  = threadIdx.x;          // 256 threads, 2 floats each
    const int* ip = seqs + (size_t)bs * C_;
    float ax = 0.f, ay = 0.f;
    for (int c = 0; c < C_; c++) {
        int row = ip[c];
        if (row < 0) row = V_;     // padding_idx -> zero row
        const float2 v = *(const float2*)(emb + (size_t)row * D_ + 2 * t);
        ax += v.x; ay += v.y;
    }
    xbf[(size_t)bs * D_ + 2 * t]     = __float2bfloat16(ax);
    xbf[(size_t)bs * D_ + 2 * t + 1] = __float2bfloat16(ay);
}

// ---------------- time feature -> tf fp32 [8192][512] ----------------
__global__ void k_tf(const float* __restrict__ stime, const float* __restrict__ selw,
                     const float* __restrict__ selb, const float* __restrict__ timew,
                     const float* __restrict__ timeb, float* __restrict__ tf)
{
    int bs = blockIdx.x;
    int t  = threadIdx.x;          // 128
    __shared__ float s1[64];
    float tv = stime[bs] * (1.0f / 180.0f);
    if (t < 64) {
        float u = tv * selw[t] + selb[t];
        s1[t] = 1.0f - tanhf(u * u);
    }
    __syncthreads();
    for (int d = t; d < D_; d += 128) {
        float a = timeb[d];
        const float* wr = timew + (size_t)d * 64;
        #pragma unroll 8
        for (int j = 0; j < 64; j++) a += s1[j] * wr[j];
        tf[(size_t)bs * D_ + d] = a;
    }
}

// ---------------- ux GEMM: [8192][512]bf16 x [2048][512]bf16^T -> [8192][2048]fp32 ----
// LDS-less: A and B fragments loaded directly from global in MFMA layouts.
__global__ __launch_bounds__(512) void k_gemm(const __bf16* __restrict__ A,
                                              const __bf16* __restrict__ Bm,
                                              float* __restrict__ Cg)
{
    int lane = threadIdx.x & 63;
    int w    = threadIdx.x >> 6;     // 8 waves
    int wm = w & 3, wn = w >> 2;     // 4 (M) x 2 (N) wave grid; wave tile 32x64
    int q = lane >> 4, r = lane & 15;
    int m0 = blockIdx.y * 128 + wm * 32;
    int n0 = blockIdx.x * 128 + wn * 64;

    const __bf16* pa0 = A  + (size_t)(m0 + r) * 512 + q * 8;
    const __bf16* pa1 = pa0 + (size_t)16 * 512;
    const __bf16* pb  = Bm + (size_t)(n0 + r) * 512 + q * 8;

    f32x4 acc[2][4] = {};
    for (int k = 0; k < 512; k += 32) {
        bf16x8 a0 = *(const bf16x8*)(pa0 + k);
        bf16x8 a1 = *(const bf16x8*)(pa1 + k);
        bf16x8 b0 = *(const bf16x8*)(pb + k);
        bf16x8 b1 = *(const bf16x8*)(pb + (size_t)16 * 512 + k);
        bf16x8 b2 = *(const bf16x8*)(pb + (size_t)32 * 512 + k);
        bf16x8 b3 = *(const bf16x8*)(pb + (size_t)48 * 512 + k);
        acc[0][0] = __builtin_amdgcn_mfma_f32_16x16x32_bf16(a0, b0, acc[0][0], 0, 0, 0);
        acc[0][1] = __builtin_amdgcn_mfma_f32_16x16x32_bf16(a0, b1, acc[0][1], 0, 0, 0);
        acc[0][2] = __builtin_amdgcn_mfma_f32_16x16x32_bf16(a0, b2, acc[0][2], 0, 0, 0);
        acc[0][3] = __builtin_amdgcn_mfma_f32_16x16x32_bf16(a0, b3, acc[0][3], 0, 0, 0);
        acc[1][0] = __builtin_amdgcn_mfma_f32_16x16x32_bf16(a1, b0, acc[1][0], 0, 0, 0);
        acc[1][1] = __builtin_amdgcn_mfma_f32_16x16x32_bf16(a1, b1, acc[1][1], 0, 0, 0);
        acc[1][2] = __builtin_amdgcn_mfma_f32_16x16x32_bf16(a1, b2, acc[1][2], 0, 0, 0);
        acc[1][3] = __builtin_amdgcn_mfma_f32_16x16x32_bf16(a1, b3, acc[1][3], 0, 0, 0);
    }
    // C/D layout: col = lane&15, row = (lane>>4)*4 + reg  [verified m89]
    for (int am = 0; am < 2; am++)
        for (int bn = 0; bn < 4; bn++) {
            int row = m0 + am * 16 + q * 4;
            int col = n0 + bn * 16 + r;
            float* cp = Cg + (size_t)row * 2048 + col;
            #pragma unroll
            for (int t = 0; t < 4; t++) cp[(size_t)t * 2048] = acc[am][bn][t];
        }
}

// ---------------- recurrence ----------------
__device__ __forceinline__ float dp2(int h, int w, float acc)
{
#if __has_builtin(__builtin_amdgcn_fdot2)
    return __builtin_amdgcn_fdot2(__builtin_bit_cast(v2h, h),
                                  __builtin_bit_cast(v2h, w), acc, false);
#else
    v2h a = __builtin_bit_cast(v2h, h), b = __builtin_bit_cast(v2h, w);
    return acc + (float)a.x * (float)b.x + (float)a.y * (float)b.y;
#endif
}

__device__ __forceinline__ float dot8(int4 h, int4 w, float acc)
{
    acc = dp2(h.x, w.x, acc);
    acc = dp2(h.y, w.y, acc);
    acc = dp2(h.z, w.z, acc);
    acc = dp2(h.w, w.w, acc);
    return acc;
}

// One block per batch element; thread d owns hidden column d (all 4 gate rows + W_d row).
__global__ __launch_bounds__(512) void k_rnn(
    const _Float16* __restrict__ Wg, const _Float16* __restrict__ Wd,
    const float* __restrict__ cb, const float* __restrict__ wdb,
    const float* __restrict__ ux, const float* __restrict__ tf,
    const float* __restrict__ outw, const float* __restrict__ outb,
    float* __restrict__ out)
{
    int b = blockIdx.x;
    int d = threadIdx.x;
    __shared__ __align__(16) _Float16 hh[512];
    __shared__ __align__(16) _Float16 ch[512];
    __shared__ float red[16];

    hh[d] = (_Float16)0.f;
    ch[d] = (_Float16)0.f;
    float c = 0.f;
    float pooled = -1e30f;
    float cbf = cb[d], cbi = cb[512 + d], cbo = cb[1024 + d], cbc = cb[1536 + d];
    float bd  = wdb[d];

    const int4* pf = (const int4*)(Wg + (size_t)d * 8);
    const int4* pi = (const int4*)(Wg + (size_t)262144 + (size_t)d * 8);
    const int4* po = (const int4*)(Wg + (size_t)524288 + (size_t)d * 8);
    const int4* pc = (const int4*)(Wg + (size_t)786432 + (size_t)d * 8);
    const int4* pd = (const int4*)(Wd + (size_t)d * 8);
    const int4* ph  = (const int4*)hh;
    const int4* pch = (const int4*)ch;

    __syncthreads();
    for (int s = 0; s < S_; s++) {
        float af = 0.f, ai = 0.f, ao = 0.f, ac = 0.f, ads = 0.f;
        #pragma unroll 4
        for (int k8 = 0; k8 < 64; k8++) {
            int4 hv = ph[k8];
            int4 cv = pch[k8];
            size_t o = (size_t)k8 * 512;   // int4 stride between k8 tiles
            af  = dot8(hv, pf[o], af);
            ai  = dot8(hv, pi[o], ai);
            ao  = dot8(hv, po[o], ao);
            ac  = dot8(hv, pc[o], ac);
            ads = dot8(cv, pd[o], ads);
        }
        int bs = b * S_ + s;
        const float* u = ux + (size_t)bs * 2048 + d;
        float gf = 1.f / (1.f + expf(-(af + cbf + u[0])));
        float gi = 1.f / (1.f + expf(-(ai + cbi + u[512])));
        float go = 1.f / (1.f + expf(-(ao + cbo + u[1024])));
        float gc = 1.f / (1.f + expf(-(ac + cbc + u[1536])));
        float cs1 = tanhf(ads + bd);
        float tfv = tf[(size_t)bs * D_ + d];
        float cadj = c - cs1 + cs1 * tfv;
        float cn = gf * cadj + gi * gc;
        float hn = go * tanhf(cn);
        pooled = fmaxf(pooled, hn);
        __syncthreads();              // everyone done reading old h/c
        hh[d] = (_Float16)hn;
        ch[d] = (_Float16)cn;
        c = cn;
        __syncthreads();              // new h/c visible
    }

    // epilogue: out[b][j] = sum_d pooled[d]*out_w[j][d] + out_b[j]
    float p0 = pooled * outw[d];
    float p1 = pooled * outw[512 + d];
    for (int off = 32; off > 0; off >>= 1) {
        p0 += __shfl_down(p0, off, 64);
        p1 += __shfl_down(p1, off, 64);
    }
    int wv = d >> 6;
    if ((d & 63) == 0) { red[wv] = p0; red[8 + wv] = p1; }
    __syncthreads();
    if (d == 0) {
        float a0 = outb[0], a1 = outb[1];
        for (int k = 0; k < 8; k++) { a0 += red[k]; a1 += red[8 + k]; }
        out[2 * b]     = a0;
        out[2 * b + 1] = a1;
    }
}

// ---------------- launch ----------------
extern "C" void kernel_launch(void* const* d_in, const int* in_sizes, int n_in,
                              void* d_out, int out_size, void* d_ws, size_t ws_size,
                              hipStream_t stream)
{
    const float* emb   = (const float*)d_in[0];
    const float* Wall  = (const float*)d_in[1];
    const float* Wallb = (const float*)d_in[2];
    const float* Uall  = (const float*)d_in[3];
    const float* Uallb = (const float*)d_in[4];
    const float* Wdw   = (const float*)d_in[5];
    const float* Wdb   = (const float*)d_in[6];
    const float* selw  = (const float*)d_in[7];
    const float* selb  = (const float*)d_in[8];
    const float* timew = (const float*)d_in[9];
    const float* timeb = (const float*)d_in[10];
    const float* outw  = (const float*)d_in[11];
    const float* outb  = (const float*)d_in[12];
    const float* stime = (const float*)d_in[13];
    const int*   seqs  = (const int*)d_in[14];
    float* out = (float*)d_out;
    char*  ws  = (char*)d_ws;

    __hip_bfloat16* xbf = (__hip_bfloat16*)(ws + OFF_XBF);
    __hip_bfloat16* ubf = (__hip_bfloat16*)(ws + OFF_UBF);
    _Float16* wg  = (_Float16*)(ws + OFF_WG);
    _Float16* wd  = (_Float16*)(ws + OFF_WD);
    float* cbp = (float*)(ws + OFF_CB);
    float* tfp = (float*)(ws + OFF_TF);
    float* uxp = (float*)(ws + OFF_UX);

    k_prep_wall<<<4096, 256, 0, stream>>>(Wall, wg);
    k_prep_wd  <<<1024, 256, 0, stream>>>(Wdw, wd);
    k_prep_u   <<<4096, 256, 0, stream>>>(Uall, ubf);
    k_prep_cb  <<<8,    256, 0, stream>>>(Wallb, Uallb, cbp);
    k_embed    <<<B_ * S_, 256, 0, stream>>>(emb, seqs, xbf);
    k_tf       <<<B_ * S_, 128, 0, stream>>>(stime, selw, selb, timew, timeb, tfp);
    k_gemm     <<<dim3(16, 64), 512, 0, stream>>>((const __bf16*)xbf, (const __bf16*)ubf, uxp);
    k_rnn      <<<B_, 512, 0, stream>>>(wg, wd, cbp, Wdb, uxp, tfp, outw, outb, out);
}